// Round 6
// baseline (14216.348 us; speedup 1.0000x reference)
//
#include <hip/hip_runtime.h>
#include <math.h>

#define BB 128
#define TT 1024
#define FF 64
#define HH 512
#define G4 2048            // 4*HH gate rows
#define NI 8               // batch groups (independent)
#define NJ 32              // hidden slices per group (16 units each)
#define BT 16
#define NBLK 256
#define LDK 520            // padded LDS row (u16): 1040B stride
#define SENT 0xFFFFFFFFu   // impossible packed h (hi = bf16 NaN)

typedef float f32x4 __attribute__((ext_vector_type(4)));
typedef short s16x8 __attribute__((ext_vector_type(8)));
typedef unsigned short u16;
typedef unsigned int u32;
typedef unsigned long long u64;

// ---- canonical inputs (ts pre-split into bf16 hi/lo planes) ----
__device__ u16 g_tsh[BB * TT * FF];
__device__ u16 g_tsl[BB * TT * FF];
__device__ float g_wihe[G4 * FF];
__device__ float g_whhe[G4 * HH];
__device__ float g_bihe[G4], g_bhhe[G4], g_bihd[G4], g_bhhd[G4];
__device__ float g_wihd[G4 * FF];
__device__ float g_whhd[G4 * HH];
__device__ float g_wout[FF * HH];
__device__ float g_bout[FF];
// ---- precomputed fused decoder weights ----
__device__ float g_weff[G4 * HH];
__device__ float g_beff[G4];
// ---- inter-block state (agent-scope atomics only; h self-flags via SENT) ----
__device__ __align__(16) u64 g_hpak[2 * BB * HH];              // 4-slot ring (u64 units)
__device__ __align__(16) float g_part[4 * NI * NJ * BT * FF];  // depth-4 ring
__device__ int   g_isbf16;

__device__ __forceinline__ float bf2f(u16 u) {
  union { unsigned u; float f; } x; x.u = ((unsigned)u) << 16; return x.f;
}
__device__ __forceinline__ u16 f2bf(float f) {
  union { float f; unsigned u; } x; x.f = f;
  unsigned r = x.u + 0x7fffu + ((x.u >> 16) & 1u);
  return (u16)(r >> 16);
}
// fast activations: 1-instr v_exp + v_rcp; saturate correctly at +/-inf
__device__ __forceinline__ float fsig(float x) {
  return __builtin_amdgcn_rcpf(1.f + __expf(-x));
}
__device__ __forceinline__ float ftanh(float x) {
  return 1.f - 2.f * __builtin_amdgcn_rcpf(__expf(2.f * x) + 1.f);
}

__global__ void sniff_kernel(const void* wout) {
  __shared__ int cnt[64];
  int t = threadIdx.x;
  const unsigned* d = (const unsigned*)wout;
  int c = 0;
  for (int k = t; k < 1024; k += 64) {
    unsigned b = (d[k] >> 8) & 0x7fu;
    c += (b >= 0x30u && b <= 0x3eu) ? 1 : 0;
  }
  cnt[t] = c;
  __syncthreads();
  if (t == 0) {
    int s = 0;
    for (int k = 0; k < 64; ++k) s += cnt[k];
    g_isbf16 = (s > 512) ? 1 : 0;
  }
}

__global__ void convert_kernel(const void* __restrict__ src, int which, int n) {
  int idx = blockIdx.x * 256 + threadIdx.x;
  if (idx >= n) return;
  float v;
  if (g_isbf16) v = bf2f(((const u16*)src)[idx]);
  else          v = ((const float*)src)[idx];
  if (which == 0) {               // ts -> bf16 hi/lo planes (encoder loads raw fragments)
    u16 hi = f2bf(v);
    g_tsh[idx] = hi;
    g_tsl[idx] = f2bf(v - bf2f(hi));
    return;
  }
  float* dst;
  switch (which) {
    case 1: dst = g_wihe; break;
    case 2: dst = g_whhe; break;
    case 3: dst = g_bihe; break;
    case 4: dst = g_bhhe; break;
    case 5: dst = g_wihd; break;
    case 6: dst = g_whhd; break;
    case 7: dst = g_bihd; break;
    case 8: dst = g_bhhd; break;
    case 9: dst = g_wout; break;
    default: dst = g_bout; break;
  }
  dst[idx] = v;
}

__global__ void prep_kernel() {
  int idx = blockIdx.x * 256 + threadIdx.x;
  int r = idx >> 9, c = idx & 511;
  float acc = g_whhd[idx];
  const float* wr = &g_wihd[r * FF];
  for (int f = 0; f < FF; ++f) acc += wr[f] * g_wout[f * HH + c];
  g_weff[idx] = acc;
  if (idx < G4) {
    float b = g_bihd[idx] + g_bhhd[idx];
    for (int f = 0; f < FF; ++f) b += g_wihd[idx * FF + f] * g_bout[f];
    g_beff[idx] = b;
  }
}

// per-launch ring init (u64 units): slot 0 = h(0)=0 (legit), slots 1-3 = sentinel.
__global__ void hinit_kernel() {
  int idx = blockIdx.x * 256 + threadIdx.x;   // 0 .. 2*BB*HH-1
  g_hpak[idx] = (idx < (BB * HH / 2)) ? 0ull : 0xFFFFFFFFFFFFFFFFull;
}

#define MFMA __builtin_amdgcn_mfma_f32_16x16x32_bf16
#define A_LD(p)  __hip_atomic_load((p), __ATOMIC_RELAXED, __HIP_MEMORY_SCOPE_AGENT)
#define A_ST(p, v) __hip_atomic_store((p), (v), __ATOMIC_RELAXED, __HIP_MEMORY_SCOPE_AGENT)

// Raw barrier: LDS ordering only. __syncthreads() would drain vmcnt(0) every
// time (store-acks ~1-2k cy) — keep vmem drains off the critical path.
#define BAR() do { asm volatile("s_waitcnt lgkmcnt(0)" ::: "memory"); \
                   __builtin_amdgcn_s_barrier(); } while (0)

// WAVE-COALESCED poll: load #(4R+j2) across 64 lanes covers 512B CONTIGUOUS
// (lane l at +l). Strided layouts inflate uncacheable (agent) loads ~8x at
// the fabric (R4/R5 evidence).
#define LDR(R) do { \
    q[4*(R)+0] = A_LD(ph + (R)*256 +   0); \
    q[4*(R)+1] = A_LD(ph + (R)*256 +  64); \
    q[4*(R)+2] = A_LD(ph + (R)*256 + 128); \
    q[4*(R)+3] = A_LD(ph + (R)*256 + 192); } while (0)
#define BADR(R) ( ((u32)q[4*(R)+0]==SENT) | ((u32)(q[4*(R)+0]>>32)==SENT) | \
                  ((u32)q[4*(R)+1]==SENT) | ((u32)(q[4*(R)+1]>>32)==SENT) | \
                  ((u32)q[4*(R)+2]==SENT) | ((u32)(q[4*(R)+2]>>32)==SENT) | \
                  ((u32)q[4*(R)+3]==SENT) | ((u32)(q[4*(R)+3]>>32)==SENT) )

__global__ __launch_bounds__(256, 1) void lstm_persist(void* __restrict__ outv) {
  // double-buffered h staging: one stage barrier per step; dbuf prevents
  // unpack(g+1) racing MFMA-reads(g).
  __shared__ u16 sHB[2][32 * LDK];  // rows 0-15: h_hi, 16-31: h_lo (linear layout)
  __shared__ float sHn[16][17];     // h_new f32 for y-partials
  __shared__ float sWoT[16][64];    // TRANSPOSED w_out slice: sWoT[n][f]

  const int tid = threadIdx.x, bid = blockIdx.x;
  const int i = bid & 7, j = bid >> 3;      // group i ~ XCD-affine, j 0..31
  const int wv = tid >> 6, lane = tid & 63;
  const int ln15 = lane & 15, lq = lane >> 4;
  // gaterow assignment: wave wv owns units {4wv..4wv+3}; lane col c=ln15
  // encodes (gate gc = c>>2, unit uc = c&3). All 4 gates of a unit live in the
  // SAME wave -> gate exchange is a 2-stage shfl_xor butterfly, no LDS/barrier.
  const int gc = ln15 >> 2, uc = ln15 & 3;
  const int gr0 = gc * 512 + (j << 4) + (wv << 2) + uc;
  const int tb = gc;                            // transpose row-block index
  const int b_own = 4 * lq + tb;                // this lane's batch row (post-butterfly)
  const int u_own = (wv << 2) + uc;             // this lane's unit within block
  const size_t colrow = (size_t)(i * BT + b_own) * (HH / 2) + (j << 3) + (u_own >> 1);
  const bool isbf = (g_isbf16 != 0);

  // ---- hidden weights -> registers (hi/lo bf16), encoder phase ----
  s16x8 wh[16], wl[16];
#pragma unroll
  for (int kt = 0; kt < 16; ++kt) {
    const float* p = &g_whhe[(size_t)gr0 * HH + kt * 32 + lq * 8];
#pragma unroll
    for (int q2 = 0; q2 < 8; ++q2) {
      float w = p[q2]; u16 hi = f2bf(w);
      wh[kt][q2] = (short)hi; wl[kt][q2] = (short)f2bf(w - bf2f(hi));
    }
  }
  s16x8 bxh0, bxh1, bxl0, bxl1;   // encoder x-weight fragments
  {
    const float* p0 = &g_wihe[(size_t)gr0 * FF + lq * 8];
#pragma unroll
    for (int q2 = 0; q2 < 8; ++q2) {
      float w0 = p0[q2], w1 = p0[32 + q2];
      u16 h0 = f2bf(w0), h1 = f2bf(w1);
      bxh0[q2] = (short)h0; bxl0[q2] = (short)f2bf(w0 - bf2f(h0));
      bxh1[q2] = (short)h1; bxl1[q2] = (short)f2bf(w1 - bf2f(h1));
    }
  }
  for (int idx = tid; idx < 16 * 64; idx += 256) {
    int n = idx >> 6, f = idx & 63;
    sWoT[n][f] = g_wout[f * HH + (j << 4) + n];
  }
  float bias = g_bihe[gr0] + g_bhhe[gr0];

  // ---- emission geometry (balanced across ALL 32 j-blocks, 256 threads) ----
  const int e_jj = tid & 31;                 // partial-slice index
  const int e_cell = (j << 3) + (tid >> 5);  // 0..255 output cell (mm, ffq)
  const int e_mm = e_cell >> 4, e_ff = (e_cell & 15) << 2;
  const float eb0 = g_bout[e_ff + 0], eb1 = g_bout[e_ff + 1];
  const float eb2 = g_bout[e_ff + 2], eb3 = g_bout[e_ff + 3];

  float c_st = 0.f;
  const int arow = ln15 * LDK;
  const int koff = lq * 8;

  // ---- PIPELINED poll state: q[] holds the in-flight round for slot g&3.
  // Issue happens at mid-iteration g-1 (right after publish h(g)), so the
  // first round's ~700-900cy fabric latency hides under the partials/emit
  // tail instead of sitting on the critical path. (R4's version of this
  // regressed only because its per-instruction STRIDED retries were 8x
  // fabric-inflated; coalesced rounds are cheap.)
  u64 q[16];
  {
    const u64* ph = g_hpak + (size_t)(i * BT + (wv << 2)) * (HH / 2) + lane;
    LDR(0); LDR(1); LDR(2); LDR(3);   // slot 0 holds h(0)=0 from hinit
  }

  for (int g = 0; g <= 2048; ++g) {
    const bool run = (g < 2048);
    float hn = 0.f;
    u64 e0 = 0, e1 = 0;
    const bool demit = (g >= 1025);

    if (!run && demit) {   // final drain iteration: issue emit loads up front
      const int slot = (g - 2) & 3;
      const u64* psrc = (const u64*)&g_part[
          (size_t)((((slot * NI) + i) * NJ + e_jj) * BT + e_mm) * FF + e_ff];
      e0 = A_LD(psrc + 0); e1 = A_LD(psrc + 1);
    }

    if (run) {
      const bool enc = (g < 1024);
      // encoder inputs: raw bf16 hi/lo fragments (pre-split at setup)
      s16x8 xh0 = {}, xl0 = {}, xh1 = {}, xl1 = {};
      if (enc) {
        const size_t xo = ((size_t)(i * BT + ln15) * TT + g) * FF + lq * 8;
        xh0 = *(const s16x8*)&g_tsh[xo];
        xh1 = *(const s16x8*)&g_tsh[xo + 32];
        xl0 = *(const s16x8*)&g_tsl[xo];
        xl1 = *(const s16x8*)&g_tsl[xo + 32];
      }

      // ---- CHECK h(g) (round already in flight since iteration g-1).
      // First retry immediate (data is ~1 step stale); then s_sleep-paced.
      {
        const u64* ph = g_hpak
            + (size_t)((g & 3) * BB + i * BT + (wv << 2)) * (HH / 2) + lane;
        bool b0 = BADR(0), b1 = BADR(1), b2 = BADR(2), b3 = BADR(3);
        if (b0 | b1 | b2 | b3) {
          if (b0) LDR(0);
          if (b1) LDR(1);
          if (b2) LDR(2);
          if (b3) LDR(3);
          if (b0) b0 = BADR(0);
          if (b1) b1 = BADR(1);
          if (b2) b2 = BADR(2);
          if (b3) b3 = BADR(3);
          while (b0 | b1 | b2 | b3) {
            __builtin_amdgcn_s_sleep(1);
            if (b0) { LDR(0); b0 = BADR(0); }
            if (b1) { LDR(1); b1 = BADR(1); }
            if (b2) { LDR(2); b2 = BADR(2); }
            if (b3) { LDR(3); b3 = BADR(3); }
          }
        }
      }
      // unpack packed u32 -> hi/lo LDS planes (v_perm); linear scatter,
      // lane-consecutive ds_write_b32 (conflict-free)
      {
        u16* sHw = &sHB[g & 1][0];
#pragma unroll
        for (int r = 0; r < 4; ++r) {
          const int row = (wv << 2) + r;
#pragma unroll
          for (int j2 = 0; j2 < 4; ++j2) {
            u64 v = q[4 * r + j2];
            u32 w0 = (u32)v, w1 = (u32)(v >> 32);
            u32 hi = __builtin_amdgcn_perm(w1, w0, 0x05040100u);
            u32 lo = __builtin_amdgcn_perm(w1, w0, 0x07060302u);
            const int u0 = 128 * j2 + 2 * lane;
            *(u32*)&sHw[row * LDK + u0] = hi;
            *(u32*)&sHw[(16 + row) * LDK + u0] = lo;
          }
        }
      }
      BAR();   // lgkmcnt-only barrier: NO vmem drain on the critical path

      // 6 accumulator chains: MFMA dep latency fully hidden
      f32x4 a0a = {bias, bias, bias, bias};
      f32x4 a0b = {0.f,0.f,0.f,0.f}, a1a = {0.f,0.f,0.f,0.f}, a1b = {0.f,0.f,0.f,0.f};
      f32x4 a2a = {0.f,0.f,0.f,0.f}, a2b = {0.f,0.f,0.f,0.f};
      const u16* sHb = &sHB[g & 1][0];
#pragma unroll
      for (int kt = 0; kt < 16; kt += 2) {
        {
          s16x8 ah = *(const s16x8*)&sHb[arow + kt * 32 + koff];
          s16x8 al = *(const s16x8*)&sHb[16 * LDK + arow + kt * 32 + koff];
          a0a = MFMA(ah, wh[kt], a0a, 0, 0, 0);
          a1a = MFMA(al, wh[kt], a1a, 0, 0, 0);
          a2a = MFMA(ah, wl[kt], a2a, 0, 0, 0);
        }
        {
          s16x8 ah = *(const s16x8*)&sHb[arow + (kt + 1) * 32 + koff];
          s16x8 al = *(const s16x8*)&sHb[16 * LDK + arow + (kt + 1) * 32 + koff];
          a0b = MFMA(ah, wh[kt + 1], a0b, 0, 0, 0);
          a1b = MFMA(al, wh[kt + 1], a1b, 0, 0, 0);
          a2b = MFMA(ah, wl[kt + 1], a2b, 0, 0, 0);
        }
      }
      if (enc) {
        a0a = MFMA(xh0, bxh0, a0a, 0, 0, 0);
        a0b = MFMA(xh1, bxh1, a0b, 0, 0, 0);
        a1a = MFMA(xl0, bxh0, a1a, 0, 0, 0);
        a1b = MFMA(xl1, bxh1, a1b, 0, 0, 0);
        a2a = MFMA(xh0, bxl0, a2a, 0, 0, 0);
        a2b = MFMA(xh1, bxl1, a2b, 0, 0, 0);
      }
      f32x4 vs = (a0a + a0b) + (a1a + a1b) + (a2a + a2b);

      // ---- in-register 4x4 gate transpose (butterfly over lane bits 2,3) ----
      float A0 = vs.x, A1 = vs.y, A2 = vs.z, A3 = vs.w;
      float t0 = __shfl_xor(A2, 8), t1 = __shfl_xor(A3, 8);
      float t2 = __shfl_xor(A0, 8), t3 = __shfl_xor(A1, 8);
      const bool hi2 = (tb & 2) != 0;
      float B0 = hi2 ? t0 : A0, B1 = hi2 ? t1 : A1;
      float B2 = hi2 ? A2 : t2, B3 = hi2 ? A3 : t3;
      float u0 = __shfl_xor(B1, 4), u1 = __shfl_xor(B0, 4);
      float u2 = __shfl_xor(B3, 4), u3 = __shfl_xor(B2, 4);
      const bool hi1 = (tb & 1) != 0;
      float gi = hi1 ? u0 : B0, gf = hi1 ? B1 : u1;
      float gg = hi1 ? u2 : B2, go = hi1 ? B3 : u3;

      float si = fsig(gi), sf = fsig(gf), tg = ftanh(gg), so_ = fsig(go);
      c_st = sf * c_st + si * tg;
      hn = so_ * ftanh(c_st);
      {
        u16 h0p = f2bf(hn), l0p = f2bf(hn - bf2f(h0p));
        u32 pak = (u32)h0p | ((u32)l0p << 16);
        u32 oth = __shfl_down(pak, 1);   // pair with unit u_own+1 (lane+1)
        // single per-step drain: partials(g-1)/outputs retired before h(g+1)
        // publishes. Outstanding stores here are ~1 step old -> near-free.
        // (Poll loads for slot g were consumed above; next slot's loads are
        // issued AFTER this drain so it never waits on them.)
        asm volatile("s_waitcnt vmcnt(0)" ::: "memory");
        if ((ln15 & 1) == 0) {
          A_ST(&g_hpak[(size_t)(((g + 1) & 3)) * (BB * HH / 2) + colrow],
               (u64)pak | ((u64)oth << 32));
          // re-sentinel slot (g+3)&3: same thread+address as its future publish
          A_ST(&g_hpak[(size_t)(((g + 3) & 3)) * (BB * HH / 2) + colrow],
               0xFFFFFFFFFFFFFFFFull);
        }
      }
      // ---- PIPELINED POLL ISSUE for slot g+1: latency hides under the
      // partials/emit tail + other producers' store-visibility window.
      if (g < 2047) {
        const u64* ph = g_hpak
            + (size_t)((((g + 1) & 3)) * BB + i * BT + (wv << 2)) * (HH / 2) + lane;
        LDR(0); LDR(1); LDR(2); LDR(3);
      }
      // emit loads (issued post-publish; consumed after the partials block)
      if (demit) {
        const int slot = (g - 2) & 3;
        const u64* psrc = (const u64*)&g_part[
            (size_t)((((slot * NI) + i) * NJ + e_jj) * BT + e_mm) * FF + e_ff];
        e0 = A_LD(psrc + 0); e1 = A_LD(psrc + 1);
      }
    }

    // ---- off-critical-path: y-partials (2-step lag to emission) ----
    if (g >= 1023 && g < 2047) {   // partials of this step's h, slot g&3
      sHn[b_own][u_own] = hn;
      BAR();
      const int fg = tid & 15, mm = tid >> 4;
      float p0 = 0.f, p1 = 0.f, p2 = 0.f, p3 = 0.f;
#pragma unroll
      for (int n = 0; n < 16; ++n) {
        float hv = sHn[mm][n];
        const f32x4 w = *(const f32x4*)&sWoT[n][fg << 2];   // b128, conflict-free
        p0 += hv * w.x; p1 += hv * w.y; p2 += hv * w.z; p3 += hv * w.w;
      }
      union { float f[4]; u64 d[2]; } pu;
      pu.f[0] = p0; pu.f[1] = p1; pu.f[2] = p2; pu.f[3] = p3;
      u64* pp = (u64*)&g_part[(size_t)((((g & 3) * NI + i) * NJ + j) * BT + mm) * FF + (fg << 2)];
      A_ST(pp + 0, pu.d[0]); A_ST(pp + 1, pu.d[1]);
    }
    if (demit) {   // consume emit loads (latency hidden under partials block)
      const int k = g - 1025;
      union { u64 d[2]; float f[4]; } uu; uu.d[0] = e0; uu.d[1] = e1;
      float s0 = uu.f[0], s1 = uu.f[1], s2 = uu.f[2], s3 = uu.f[3];
#pragma unroll
      for (int m = 16; m >= 1; m >>= 1) {      // reduce over the 32 e_jj lanes
        s0 += __shfl_xor(s0, m); s1 += __shfl_xor(s1, m);
        s2 += __shfl_xor(s2, m); s3 += __shfl_xor(s3, m);
      }
      if (e_jj == 0) {
        float o0 = s0 + eb0, o1 = s1 + eb1, o2 = s2 + eb2, o3 = s3 + eb3;
        size_t oidx = ((size_t)(i * BT + e_mm) * TT + (1023 - k)) * FF + e_ff;
        if (isbf) {
          union { u16 h[4]; u64 d; } ov;
          ov.h[0] = f2bf(o0); ov.h[1] = f2bf(o1); ov.h[2] = f2bf(o2); ov.h[3] = f2bf(o3);
          *(u64*)((u16*)outv + oidx) = ov.d;
        } else {
          f32x4 ov = {o0, o1, o2, o3};
          *(f32x4*)((float*)outv + oidx) = ov;
        }
      }
    }

    // phase switch: reload registers with fused decoder weights
    if (g == 1023) {
#pragma unroll
      for (int kt = 0; kt < 16; ++kt) {
        const float* p = &g_weff[(size_t)gr0 * HH + kt * 32 + lq * 8];
#pragma unroll
        for (int q2 = 0; q2 < 8; ++q2) {
          float w = p[q2]; u16 hi = f2bf(w);
          wh[kt][q2] = (short)hi; wl[kt][q2] = (short)f2bf(w - bf2f(hi));
        }
      }
      bias = g_beff[gr0];
      c_st = 0.f;
    }
  }
}

extern "C" void kernel_launch(void* const* d_in, const int* in_sizes, int n_in,
                              void* d_out, int out_size, void* d_ws, size_t ws_size,
                              hipStream_t stream) {
  sniff_kernel<<<1, 64, 0, stream>>>(d_in[9]);  // w_out

  const int sizes[11] = { BB * TT * FF, G4 * FF, G4 * HH, G4, G4,
                          G4 * FF, G4 * HH, G4, G4, FF * HH, FF };
  for (int k = 0; k < 11; ++k)
    convert_kernel<<<(sizes[k] + 255) / 256, 256, 0, stream>>>(d_in[k], k, sizes[k]);

  prep_kernel<<<(G4 * HH) / 256, 256, 0, stream>>>();
  hinit_kernel<<<(2 * BB * HH) / 256, 256, 0, stream>>>();

  lstm_persist<<<NBLK, 256, 0, stream>>>(d_out);
}

// Round 9
// 9498.511 us; speedup vs baseline: 1.4967x; 1.4967x over previous
//
#include <hip/hip_runtime.h>
#include <math.h>

#define BB 128
#define TT 1024
#define FF 64
#define HH 512
#define G4 2048            // 4*HH gate rows
#define NI 8               // batch groups (independent)
#define NJ 32              // partial slices per group (emission granularity)
#define JB 16              // BLOCKS per group (each owns 32 units)
#define BT 16
#define NBLK 128           // 8 groups x 16 blocks
#define NTHR 512           // 8 waves
#define LDK 520            // padded LDS row (u16): 1040B stride
#define SENT 0xFFFFFFFFu   // impossible packed h (hi = bf16 NaN)

typedef float f32x4 __attribute__((ext_vector_type(4)));
typedef short s16x8 __attribute__((ext_vector_type(8)));
typedef unsigned short u16;
typedef unsigned int u32;
typedef unsigned long long u64;

// ---- canonical inputs (ts pre-split into bf16 hi/lo planes) ----
__device__ u16 g_tsh[BB * TT * FF];
__device__ u16 g_tsl[BB * TT * FF];
__device__ float g_wihe[G4 * FF];
__device__ float g_whhe[G4 * HH];
__device__ float g_bihe[G4], g_bhhe[G4], g_bihd[G4], g_bhhd[G4];
__device__ float g_wihd[G4 * FF];
__device__ float g_whhd[G4 * HH];
__device__ float g_wout[FF * HH];
__device__ float g_bout[FF];
// ---- precomputed fused decoder weights ----
__device__ float g_weff[G4 * HH];
__device__ float g_beff[G4];
// ---- inter-block state (agent-scope atomics only; h self-flags via SENT).
// R5-proven protocol: coherence point = IC; traffic is the cost driver, so
// this round halves the redundant consumer count (16 readers/group not 32).
__device__ __align__(16) u64 g_hpak[2 * BB * HH];              // 4-slot ring (u64 units)
__device__ __align__(16) float g_part[4 * NI * NJ * BT * FF];  // depth-4 ring
__device__ int g_isbf16;

__device__ __forceinline__ float bf2f(u16 u) {
  union { unsigned u; float f; } x; x.u = ((unsigned)u) << 16; return x.f;
}
__device__ __forceinline__ u16 f2bf(float f) {
  union { float f; unsigned u; } x; x.f = f;
  unsigned r = x.u + 0x7fffu + ((x.u >> 16) & 1u);
  return (u16)(r >> 16);
}
// fast activations: 1-instr v_exp + v_rcp; saturate correctly at +/-inf
__device__ __forceinline__ float fsig(float x) {
  return __builtin_amdgcn_rcpf(1.f + __expf(-x));
}
__device__ __forceinline__ float ftanh(float x) {
  return 1.f - 2.f * __builtin_amdgcn_rcpf(__expf(2.f * x) + 1.f);
}

__global__ void sniff_kernel(const void* wout) {
  __shared__ int cnt[64];
  int t = threadIdx.x;
  const unsigned* d = (const unsigned*)wout;
  int c = 0;
  for (int k = t; k < 1024; k += 64) {
    unsigned b = (d[k] >> 8) & 0x7fu;
    c += (b >= 0x30u && b <= 0x3eu) ? 1 : 0;
  }
  cnt[t] = c;
  __syncthreads();
  if (t == 0) {
    int s = 0;
    for (int k = 0; k < 64; ++k) s += cnt[k];
    g_isbf16 = (s > 512) ? 1 : 0;
  }
}

__global__ void convert_kernel(const void* __restrict__ src, int which, int n) {
  int idx = blockIdx.x * 256 + threadIdx.x;
  if (idx >= n) return;
  float v;
  if (g_isbf16) v = bf2f(((const u16*)src)[idx]);
  else          v = ((const float*)src)[idx];
  if (which == 0) {               // ts -> bf16 hi/lo planes
    u16 hi = f2bf(v);
    g_tsh[idx] = hi;
    g_tsl[idx] = f2bf(v - bf2f(hi));
    return;
  }
  float* dst;
  switch (which) {
    case 1: dst = g_wihe; break;
    case 2: dst = g_whhe; break;
    case 3: dst = g_bihe; break;
    case 4: dst = g_bhhe; break;
    case 5: dst = g_wihd; break;
    case 6: dst = g_whhd; break;
    case 7: dst = g_bihd; break;
    case 8: dst = g_bhhd; break;
    case 9: dst = g_wout; break;
    default: dst = g_bout; break;
  }
  dst[idx] = v;
}

__global__ void prep_kernel() {
  int idx = blockIdx.x * 256 + threadIdx.x;
  int r = idx >> 9, c = idx & 511;
  float acc = g_whhd[idx];
  const float* wr = &g_wihd[r * FF];
  for (int f = 0; f < FF; ++f) acc += wr[f] * g_wout[f * HH + c];
  g_weff[idx] = acc;
  if (idx < G4) {
    float b = g_bihd[idx] + g_bhhd[idx];
    for (int f = 0; f < FF; ++f) b += g_wihd[idx * FF + f] * g_bout[f];
    g_beff[idx] = b;
  }
}

// per-launch ring init (u64 units): slot 0 = h(0)=0, slots 1-3 = sentinel.
__global__ void hinit_kernel() {
  int idx = blockIdx.x * 256 + threadIdx.x;   // 0 .. 2*BB*HH-1
  g_hpak[idx] = (idx < (BB * HH / 2)) ? 0ull : 0xFFFFFFFFFFFFFFFFull;
}

#define MFMA __builtin_amdgcn_mfma_f32_16x16x32_bf16
#define A_LD(p)  __hip_atomic_load((p), __ATOMIC_RELAXED, __HIP_MEMORY_SCOPE_AGENT)
#define A_ST(p, v) __hip_atomic_store((p), (v), __ATOMIC_RELAXED, __HIP_MEMORY_SCOPE_AGENT)

// Raw barrier: LDS ordering only (no vmem drain on the critical path).
#define BAR() do { asm volatile("s_waitcnt lgkmcnt(0)" ::: "memory"); \
                   __builtin_amdgcn_s_barrier(); } while (0)

// WAVE-COALESCED poll round R (row R of this wave's 2): the 4 loads each
// cover 512B contiguous across 64 lanes (lane l at +l).
#define LDR(R) do { \
    q[4*(R)+0] = A_LD(ph + (R)*256 +   0); \
    q[4*(R)+1] = A_LD(ph + (R)*256 +  64); \
    q[4*(R)+2] = A_LD(ph + (R)*256 + 128); \
    q[4*(R)+3] = A_LD(ph + (R)*256 + 192); } while (0)
#define BADR(R) ( ((u32)q[4*(R)+0]==SENT) | ((u32)(q[4*(R)+0]>>32)==SENT) | \
                  ((u32)q[4*(R)+1]==SENT) | ((u32)(q[4*(R)+1]>>32)==SENT) | \
                  ((u32)q[4*(R)+2]==SENT) | ((u32)(q[4*(R)+2]>>32)==SENT) | \
                  ((u32)q[4*(R)+3]==SENT) | ((u32)(q[4*(R)+3]>>32)==SENT) )

__global__ __launch_bounds__(NTHR, 1) void lstm_persist(void* __restrict__ outv) {
  __shared__ u16 sHB[2][32 * LDK];  // rows 0-15: h_hi, 16-31: h_lo (linear)
  __shared__ float sHn[16][33];     // h_new f32 for y-partials (16 batch x 32 units)
  __shared__ float sWoT[32][64];    // TRANSPOSED w_out slice: sWoT[n][f]

  const int tid = threadIdx.x, bid = blockIdx.x;
  const int i = bid & 7, j = bid >> 3;      // group i ~ XCD-affine, j 0..15
  const int wv = tid >> 6, lane = tid & 63; // 8 waves
  const int ln15 = lane & 15, lq = lane >> 4;
  // wave wv owns units {4wv..4wv+3} (32 units/block); lane col c=ln15 encodes
  // (gate gc=c>>2, unit uc=c&3). Gate exchange = in-register butterfly.
  const int gc = ln15 >> 2, uc = ln15 & 3;
  const int gr0 = gc * 512 + (j << 5) + (wv << 2) + uc;
  const int tb = gc;
  const int b_own = 4 * lq + tb;                // lane's batch row (post-butterfly)
  const int u_own = (wv << 2) + uc;             // lane's unit within block (0..31)
  const size_t colrow = (size_t)(i * BT + b_own) * (HH / 2) + (j << 4) + (u_own >> 1);
  const bool isbf = (g_isbf16 != 0);

  // ---- hidden weights -> registers (hi/lo bf16), encoder phase ----
  s16x8 wh[16], wl[16];
#pragma unroll
  for (int kt = 0; kt < 16; ++kt) {
    const float* p = &g_whhe[(size_t)gr0 * HH + kt * 32 + lq * 8];
#pragma unroll
    for (int q2 = 0; q2 < 8; ++q2) {
      float w = p[q2]; u16 hi = f2bf(w);
      wh[kt][q2] = (short)hi; wl[kt][q2] = (short)f2bf(w - bf2f(hi));
    }
  }
  s16x8 bxh0, bxh1, bxl0, bxl1;   // encoder x-weight fragments
  {
    const float* p0 = &g_wihe[(size_t)gr0 * FF + lq * 8];
#pragma unroll
    for (int q2 = 0; q2 < 8; ++q2) {
      float w0 = p0[q2], w1 = p0[32 + q2];
      u16 h0 = f2bf(w0), h1 = f2bf(w1);
      bxh0[q2] = (short)h0; bxl0[q2] = (short)f2bf(w0 - bf2f(h0));
      bxh1[q2] = (short)h1; bxl1[q2] = (short)f2bf(w1 - bf2f(h1));
    }
  }
  for (int idx = tid; idx < 32 * 64; idx += NTHR) {
    int n = idx >> 6, f = idx & 63;
    sWoT[n][f] = g_wout[f * HH + (j << 5) + n];
  }
  float bias = g_bihe[gr0] + g_bhhe[gr0];

  // ---- emission geometry: 256 cells/group over 16 blocks x 16 cells;
  // all 512 threads: cell = (j<<4) + (tid>>5), slice e_jj = tid&31.
  const int e_jj = tid & 31;
  const int e_cell = (j << 4) + (tid >> 5);
  const int e_mm = e_cell >> 4, e_ff = (e_cell & 15) << 2;
  const float eb0 = g_bout[e_ff + 0], eb1 = g_bout[e_ff + 1];
  const float eb2 = g_bout[e_ff + 2], eb3 = g_bout[e_ff + 3];

  // ---- partials geometry: 512 threads = 16 mm x 16 fg x 2 halves; each half
  // sums 16 of the block's 32 units into slice j*2+half (NJ=32 total slices,
  // emission stays byte-identical to R5).
  const int p_fg = tid & 15, p_half = (tid >> 4) & 1, p_mm = tid >> 5;
  const int p_n0 = p_half << 4;

  float c_st = 0.f;
  const int arow = ln15 * LDK;
  const int koff = lq * 8;

  for (int g = 0; g <= 2048; ++g) {
    const bool run = (g < 2048);
    float hn = 0.f;
    u64 e0 = 0, e1 = 0;
    const bool demit = (g >= 1025);

    if (!run && demit) {   // final drain iteration: issue emit loads up front
      const int slot = (g - 2) & 3;
      const u64* psrc = (const u64*)&g_part[
          (size_t)((((slot * NI) + i) * NJ + e_jj) * BT + e_mm) * FF + e_ff];
      e0 = A_LD(psrc + 0); e1 = A_LD(psrc + 1);
    }

    if (run) {
      const bool enc = (g < 1024);
      // encoder inputs: raw bf16 hi/lo fragments (pre-split at setup)
      s16x8 xh0 = {}, xl0 = {}, xh1 = {}, xl1 = {};
      if (enc) {
        const size_t xo = ((size_t)(i * BT + ln15) * TT + g) * FF + lq * 8;
        xh0 = *(const s16x8*)&g_tsh[xo];
        xh1 = *(const s16x8*)&g_tsh[xo + 32];
        xl0 = *(const s16x8*)&g_tsl[xo];
        xl1 = *(const s16x8*)&g_tsl[xo + 32];
      }

      // ---- POLL-STAGE h(g) from ring slot g&3 (data self-flags).
      // 8 waves x 2 rows each; retries reload only still-bad rows.
      u64 q[8];
      {
        const u64* ph = g_hpak
            + (size_t)((g & 3) * BB + i * BT + (wv << 1)) * (HH / 2) + lane;
        LDR(0); LDR(1);
        bool b0 = BADR(0), b1 = BADR(1);
        while (b0 | b1) {
          __builtin_amdgcn_s_sleep(1);
          if (b0) { LDR(0); b0 = BADR(0); }
          if (b1) { LDR(1); b1 = BADR(1); }
        }
      }
      // unpack packed u32 -> hi/lo LDS planes (v_perm); lane-consecutive
      // ds_write_b32 (conflict-free)
      {
        u16* sHw = &sHB[g & 1][0];
#pragma unroll
        for (int r = 0; r < 2; ++r) {
          const int row = (wv << 1) + r;
#pragma unroll
          for (int k = 0; k < 4; ++k) {
            u64 v = q[4 * r + k];
            u32 w0 = (u32)v, w1 = (u32)(v >> 32);
            u32 hi = __builtin_amdgcn_perm(w1, w0, 0x05040100u);
            u32 lo = __builtin_amdgcn_perm(w1, w0, 0x07060302u);
            const int u0 = 128 * k + 2 * lane;
            *(u32*)&sHw[row * LDK + u0] = hi;
            *(u32*)&sHw[(16 + row) * LDK + u0] = lo;
          }
        }
      }
      BAR();   // lgkmcnt-only barrier

      // 6 accumulator chains: MFMA dep latency fully hidden
      f32x4 a0a = {bias, bias, bias, bias};
      f32x4 a0b = {0.f,0.f,0.f,0.f}, a1a = {0.f,0.f,0.f,0.f}, a1b = {0.f,0.f,0.f,0.f};
      f32x4 a2a = {0.f,0.f,0.f,0.f}, a2b = {0.f,0.f,0.f,0.f};
      const u16* sHb = &sHB[g & 1][0];
#pragma unroll
      for (int kt = 0; kt < 16; kt += 2) {
        {
          s16x8 ah = *(const s16x8*)&sHb[arow + kt * 32 + koff];
          s16x8 al = *(const s16x8*)&sHb[16 * LDK + arow + kt * 32 + koff];
          a0a = MFMA(ah, wh[kt], a0a, 0, 0, 0);
          a1a = MFMA(al, wh[kt], a1a, 0, 0, 0);
          a2a = MFMA(ah, wl[kt], a2a, 0, 0, 0);
        }
        {
          s16x8 ah = *(const s16x8*)&sHb[arow + (kt + 1) * 32 + koff];
          s16x8 al = *(const s16x8*)&sHb[16 * LDK + arow + (kt + 1) * 32 + koff];
          a0b = MFMA(ah, wh[kt + 1], a0b, 0, 0, 0);
          a1b = MFMA(al, wh[kt + 1], a1b, 0, 0, 0);
          a2b = MFMA(ah, wl[kt + 1], a2b, 0, 0, 0);
        }
      }
      if (enc) {
        a0a = MFMA(xh0, bxh0, a0a, 0, 0, 0);
        a0b = MFMA(xh1, bxh1, a0b, 0, 0, 0);
        a1a = MFMA(xl0, bxh0, a1a, 0, 0, 0);
        a1b = MFMA(xl1, bxh1, a1b, 0, 0, 0);
        a2a = MFMA(xh0, bxl0, a2a, 0, 0, 0);
        a2b = MFMA(xh1, bxl1, a2b, 0, 0, 0);
      }
      f32x4 vs = (a0a + a0b) + (a1a + a1b) + (a2a + a2b);

      // ---- in-register 4x4 gate transpose (butterfly over lane bits 2,3) ----
      float A0 = vs.x, A1 = vs.y, A2 = vs.z, A3 = vs.w;
      float t0 = __shfl_xor(A2, 8), t1 = __shfl_xor(A3, 8);
      float t2 = __shfl_xor(A0, 8), t3 = __shfl_xor(A1, 8);
      const bool hi2 = (tb & 2) != 0;
      float B0 = hi2 ? t0 : A0, B1 = hi2 ? t1 : A1;
      float B2 = hi2 ? A2 : t2, B3 = hi2 ? A3 : t3;
      float u0 = __shfl_xor(B1, 4), u1 = __shfl_xor(B0, 4);
      float u2 = __shfl_xor(B3, 4), u3 = __shfl_xor(B2, 4);
      const bool hi1 = (tb & 1) != 0;
      float gi = hi1 ? u0 : B0, gf = hi1 ? B1 : u1;
      float gg = hi1 ? u2 : B2, go = hi1 ? B3 : u3;

      float si = fsig(gi), sf = fsig(gf), tg = ftanh(gg), so_ = fsig(go);
      c_st = sf * c_st + si * tg;
      hn = so_ * ftanh(c_st);
      {
        u16 h0p = f2bf(hn), l0p = f2bf(hn - bf2f(h0p));
        u32 pak = (u32)h0p | ((u32)l0p << 16);
        u32 oth = __shfl_down(pak, 1);   // pair with unit u_own+1 (lane+1)
        // single per-step drain: partials(g-1)/outputs retired before h(g+1)
        // publishes. Outstanding stores are ~1 step old -> near-free.
        asm volatile("s_waitcnt vmcnt(0)" ::: "memory");
        if ((ln15 & 1) == 0) {
          A_ST(&g_hpak[(size_t)(((g + 1) & 3)) * (BB * HH / 2) + colrow],
               (u64)pak | ((u64)oth << 32));
          // re-sentinel slot (g+3)&3: same thread+address as its future publish
          A_ST(&g_hpak[(size_t)(((g + 3) & 3)) * (BB * HH / 2) + colrow],
               0xFFFFFFFFFFFFFFFFull);
        }
      }
      // emit loads (issued post-publish; consumed after the partials block)
      if (demit) {
        const int slot = (g - 2) & 3;
        const u64* psrc = (const u64*)&g_part[
            (size_t)((((slot * NI) + i) * NJ + e_jj) * BT + e_mm) * FF + e_ff];
        e0 = A_LD(psrc + 0); e1 = A_LD(psrc + 1);
      }
    }

    // ---- off-critical-path: y-partials (2-step lag to emission) ----
    if (g >= 1023 && g < 2047) {   // partials of this step's h, slot g&3
      sHn[b_own][u_own] = hn;
      BAR();
      float p0 = 0.f, p1 = 0.f, p2 = 0.f, p3 = 0.f;
#pragma unroll
      for (int n = 0; n < 16; ++n) {
        float hv = sHn[p_mm][p_n0 + n];
        const f32x4 w = *(const f32x4*)&sWoT[p_n0 + n][p_fg << 2];
        p0 += hv * w.x; p1 += hv * w.y; p2 += hv * w.z; p3 += hv * w.w;
      }
      union { float f[4]; u64 d[2]; } pu;
      pu.f[0] = p0; pu.f[1] = p1; pu.f[2] = p2; pu.f[3] = p3;
      u64* pp = (u64*)&g_part[(size_t)((((g & 3) * NI + i) * NJ + ((j << 1) + p_half))
                                       * BT + p_mm) * FF + (p_fg << 2)];
      A_ST(pp + 0, pu.d[0]); A_ST(pp + 1, pu.d[1]);
    }
    if (demit) {   // consume emit loads (latency hidden under partials block)
      const int k = g - 1025;
      union { u64 d[2]; float f[4]; } uu; uu.d[0] = e0; uu.d[1] = e1;
      float s0 = uu.f[0], s1 = uu.f[1], s2 = uu.f[2], s3 = uu.f[3];
#pragma unroll
      for (int m = 16; m >= 1; m >>= 1) {      // reduce over the 32 e_jj lanes
        s0 += __shfl_xor(s0, m); s1 += __shfl_xor(s1, m);
        s2 += __shfl_xor(s2, m); s3 += __shfl_xor(s3, m);
      }
      if (e_jj == 0) {
        float o0 = s0 + eb0, o1 = s1 + eb1, o2 = s2 + eb2, o3 = s3 + eb3;
        size_t oidx = ((size_t)(i * BT + e_mm) * TT + (1023 - k)) * FF + e_ff;
        if (isbf) {
          union { u16 h[4]; u64 d; } ov;
          ov.h[0] = f2bf(o0); ov.h[1] = f2bf(o1); ov.h[2] = f2bf(o2); ov.h[3] = f2bf(o3);
          *(u64*)((u16*)outv + oidx) = ov.d;
        } else {
          f32x4 ov = {o0, o1, o2, o3};
          *(f32x4*)((float*)outv + oidx) = ov;
        }
      }
    }

    // phase switch: reload registers with fused decoder weights
    if (g == 1023) {
#pragma unroll
      for (int kt = 0; kt < 16; ++kt) {
        const float* p = &g_weff[(size_t)gr0 * HH + kt * 32 + lq * 8];
#pragma unroll
        for (int q2 = 0; q2 < 8; ++q2) {
          float w = p[q2]; u16 hi = f2bf(w);
          wh[kt][q2] = (short)hi; wl[kt][q2] = (short)f2bf(w - bf2f(hi));
        }
      }
      bias = g_beff[gr0];
      c_st = 0.f;
    }
  }
}

extern "C" void kernel_launch(void* const* d_in, const int* in_sizes, int n_in,
                              void* d_out, int out_size, void* d_ws, size_t ws_size,
                              hipStream_t stream) {
  sniff_kernel<<<1, 64, 0, stream>>>(d_in[9]);  // w_out

  const int sizes[11] = { BB * TT * FF, G4 * FF, G4 * HH, G4, G4,
                          G4 * FF, G4 * HH, G4, G4, FF * HH, FF };
  for (int k = 0; k < 11; ++k)
    convert_kernel<<<(sizes[k] + 255) / 256, 256, 0, stream>>>(d_in[k], k, sizes[k]);

  prep_kernel<<<(G4 * HH) / 256, 256, 0, stream>>>();
  hinit_kernel<<<(2 * BB * HH) / 256, 256, 0, stream>>>();

  lstm_persist<<<NBLK, NTHR, 0, stream>>>(d_out);
}

// Round 10
// 6370.509 us; speedup vs baseline: 2.2316x; 1.4910x over previous
//
#include <hip/hip_runtime.h>
#include <math.h>

#define BB 128
#define TT 1024
#define FF 64
#define HH 512
#define G4 2048            // 4*HH gate rows
#define NI 8               // batch groups (independent)
#define NJ 32              // hidden slices per group (16 units each)
#define BT 16
#define NBLK 256
#define LDK 520            // padded LDS row (u16): 1040B stride
#define SENT 0xFFFFFFFFu   // impossible packed h (hi = bf16 NaN)

typedef float f32x4 __attribute__((ext_vector_type(4)));
typedef short s16x8 __attribute__((ext_vector_type(8)));
typedef unsigned short u16;
typedef unsigned int u32;
typedef unsigned long long u64;

// ---- canonical inputs (ts pre-split into bf16 hi/lo planes) ----
__device__ u16 g_tsh[BB * TT * FF];
__device__ u16 g_tsl[BB * TT * FF];
__device__ float g_wihe[G4 * FF];
__device__ float g_whhe[G4 * HH];
__device__ float g_bihe[G4], g_bhhe[G4], g_bihd[G4], g_bhhd[G4];
__device__ float g_wihd[G4 * FF];
__device__ float g_whhd[G4 * HH];
__device__ float g_wout[FF * HH];
__device__ float g_bout[FF];
// ---- precomputed fused decoder weights ----
__device__ float g_weff[G4 * HH];
__device__ float g_beff[G4];
// ---- inter-block state (agent-scope atomics only; h self-flags via SENT) ----
__device__ __align__(16) u64 g_hpak[2 * BB * HH];              // 4-slot ring (u64 units)
__device__ __align__(16) float g_part[4 * NI * NJ * BT * FF];  // depth-4 ring
__device__ int g_isbf16;

__device__ __forceinline__ float bf2f(u16 u) {
  union { unsigned u; float f; } x; x.u = ((unsigned)u) << 16; return x.f;
}
__device__ __forceinline__ u16 f2bf(float f) {
  union { float f; unsigned u; } x; x.f = f;
  unsigned r = x.u + 0x7fffu + ((x.u >> 16) & 1u);
  return (u16)(r >> 16);
}
// fast activations: 1-instr v_exp + v_rcp; saturate correctly at +/-inf
__device__ __forceinline__ float fsig(float x) {
  return __builtin_amdgcn_rcpf(1.f + __expf(-x));
}
__device__ __forceinline__ float ftanh(float x) {
  return 1.f - 2.f * __builtin_amdgcn_rcpf(__expf(2.f * x) + 1.f);
}

__global__ void sniff_kernel(const void* wout) {
  __shared__ int cnt[64];
  int t = threadIdx.x;
  const unsigned* d = (const unsigned*)wout;
  int c = 0;
  for (int k = t; k < 1024; k += 64) {
    unsigned b = (d[k] >> 8) & 0x7fu;
    c += (b >= 0x30u && b <= 0x3eu) ? 1 : 0;
  }
  cnt[t] = c;
  __syncthreads();
  if (t == 0) {
    int s = 0;
    for (int k = 0; k < 64; ++k) s += cnt[k];
    g_isbf16 = (s > 512) ? 1 : 0;
  }
}

__global__ void convert_kernel(const void* __restrict__ src, int which, int n) {
  int idx = blockIdx.x * 256 + threadIdx.x;
  if (idx >= n) return;
  float v;
  if (g_isbf16) v = bf2f(((const u16*)src)[idx]);
  else          v = ((const float*)src)[idx];
  if (which == 0) {               // ts -> bf16 hi/lo planes
    u16 hi = f2bf(v);
    g_tsh[idx] = hi;
    g_tsl[idx] = f2bf(v - bf2f(hi));
    return;
  }
  float* dst;
  switch (which) {
    case 1: dst = g_wihe; break;
    case 2: dst = g_whhe; break;
    case 3: dst = g_bihe; break;
    case 4: dst = g_bhhe; break;
    case 5: dst = g_wihd; break;
    case 6: dst = g_whhd; break;
    case 7: dst = g_bihd; break;
    case 8: dst = g_bhhd; break;
    case 9: dst = g_wout; break;
    default: dst = g_bout; break;
  }
  dst[idx] = v;
}

__global__ void prep_kernel() {
  int idx = blockIdx.x * 256 + threadIdx.x;
  int r = idx >> 9, c = idx & 511;
  float acc = g_whhd[idx];
  const float* wr = &g_wihd[r * FF];
  for (int f = 0; f < FF; ++f) acc += wr[f] * g_wout[f * HH + c];
  g_weff[idx] = acc;
  if (idx < G4) {
    float b = g_bihd[idx] + g_bhhd[idx];
    for (int f = 0; f < FF; ++f) b += g_wihd[idx * FF + f] * g_bout[f];
    g_beff[idx] = b;
  }
}

// per-launch ring init (u64 units): slot 0 = h(0)=0, slots 1-3 = sentinel.
__global__ void hinit_kernel() {
  int idx = blockIdx.x * 256 + threadIdx.x;   // 0 .. 2*BB*HH-1
  g_hpak[idx] = (idx < (BB * HH / 2)) ? 0ull : 0xFFFFFFFFFFFFFFFFull;
}

#define MFMA __builtin_amdgcn_mfma_f32_16x16x32_bf16
#define A_LD(p)  __hip_atomic_load((p), __ATOMIC_RELAXED, __HIP_MEMORY_SCOPE_AGENT)
#define A_ST(p, v) __hip_atomic_store((p), (v), __ATOMIC_RELAXED, __HIP_MEMORY_SCOPE_AGENT)

// Raw barrier: LDS ordering only (no vmem drain on the critical path).
#define BAR() do { asm volatile("s_waitcnt lgkmcnt(0)" ::: "memory"); \
                   __builtin_amdgcn_s_barrier(); } while (0)

// WAVE-COALESCED poll, split by PRODUCER HALVES.
// q[4r+j2] = row (4wv+r), units [128*j2 + 2*lane, +2): each load covers 512B
// contiguous across 64 lanes. Half A = j2 0,1 (units 0-255, blocks 0-15);
// half B = j2 2,3 (units 256-511, blocks 16-31).
#define LDA(R) do { \
    q[4*(R)+0] = A_LD(ph + (R)*256 +   0); \
    q[4*(R)+1] = A_LD(ph + (R)*256 +  64); } while (0)
#define LDB(R) do { \
    q[4*(R)+2] = A_LD(ph + (R)*256 + 128); \
    q[4*(R)+3] = A_LD(ph + (R)*256 + 192); } while (0)
#define BADA(R) ( ((u32)q[4*(R)+0]==SENT) | ((u32)(q[4*(R)+0]>>32)==SENT) | \
                  ((u32)q[4*(R)+1]==SENT) | ((u32)(q[4*(R)+1]>>32)==SENT) )
#define BADB(R) ( ((u32)q[4*(R)+2]==SENT) | ((u32)(q[4*(R)+2]>>32)==SENT) | \
                  ((u32)q[4*(R)+3]==SENT) | ((u32)(q[4*(R)+3]>>32)==SENT) )

__global__ __launch_bounds__(256, 1) void lstm_persist(void* __restrict__ outv) {
  // double-buffered h staging; two lgkm-only barriers per step (one per half).
  __shared__ u16 sHB[2][32 * LDK];  // rows 0-15: h_hi, 16-31: h_lo (linear)
  __shared__ float sHn[16][17];     // h_new f32 for y-partials
  __shared__ float sWoT[16][64];    // TRANSPOSED w_out slice: sWoT[n][f]

  const int tid = threadIdx.x, bid = blockIdx.x;
  const int i = bid & 7, j = bid >> 3;      // group i ~ XCD-affine, j 0..31
  const int wv = tid >> 6, lane = tid & 63;
  const int ln15 = lane & 15, lq = lane >> 4;
  // wave wv owns units {4wv..4wv+3}; lane col c=ln15 encodes (gate gc=c>>2,
  // unit uc=c&3). Gate exchange = in-register 2-stage shfl_xor butterfly.
  const int gc = ln15 >> 2, uc = ln15 & 3;
  const int gr0 = gc * 512 + (j << 4) + (wv << 2) + uc;
  const int tb = gc;
  const int b_own = 4 * lq + tb;                // lane's batch row (post-butterfly)
  const int u_own = (wv << 2) + uc;             // lane's unit within block
  const size_t colrow = (size_t)(i * BT + b_own) * (HH / 2) + (j << 3) + (u_own >> 1);
  const bool isbf = (g_isbf16 != 0);

  // ---- hidden weights -> registers (hi/lo bf16), encoder phase ----
  s16x8 wh[16], wl[16];
#pragma unroll
  for (int kt = 0; kt < 16; ++kt) {
    const float* p = &g_whhe[(size_t)gr0 * HH + kt * 32 + lq * 8];
#pragma unroll
    for (int q2 = 0; q2 < 8; ++q2) {
      float w = p[q2]; u16 hi = f2bf(w);
      wh[kt][q2] = (short)hi; wl[kt][q2] = (short)f2bf(w - bf2f(hi));
    }
  }
  s16x8 bxh0, bxh1, bxl0, bxl1;   // encoder x-weight fragments
  {
    const float* p0 = &g_wihe[(size_t)gr0 * FF + lq * 8];
#pragma unroll
    for (int q2 = 0; q2 < 8; ++q2) {
      float w0 = p0[q2], w1 = p0[32 + q2];
      u16 h0 = f2bf(w0), h1 = f2bf(w1);
      bxh0[q2] = (short)h0; bxl0[q2] = (short)f2bf(w0 - bf2f(h0));
      bxh1[q2] = (short)h1; bxl1[q2] = (short)f2bf(w1 - bf2f(h1));
    }
  }
  for (int idx = tid; idx < 16 * 64; idx += 256) {
    int n = idx >> 6, f = idx & 63;
    sWoT[n][f] = g_wout[f * HH + (j << 4) + n];
  }
  float bias = g_bihe[gr0] + g_bhhe[gr0];

  // ---- emission geometry (balanced across ALL 32 j-blocks, 256 threads) ----
  const int e_jj = tid & 31;                 // partial-slice index
  const int e_cell = (j << 3) + (tid >> 5);  // 0..255 output cell (mm, ffq)
  const int e_mm = e_cell >> 4, e_ff = (e_cell & 15) << 2;
  const float eb0 = g_bout[e_ff + 0], eb1 = g_bout[e_ff + 1];
  const float eb2 = g_bout[e_ff + 2], eb3 = g_bout[e_ff + 3];

  float c_st = 0.f;
  const int arow = ln15 * LDK;
  const int koff = lq * 8;

  for (int g = 0; g <= 2048; ++g) {
    const bool run = (g < 2048);
    float hn = 0.f;
    u64 e0 = 0, e1 = 0;
    const bool demit = (g >= 1025);

    if (!run && demit) {   // final drain iteration: issue emit loads up front
      const int slot = (g - 2) & 3;
      const u64* psrc = (const u64*)&g_part[
          (size_t)((((slot * NI) + i) * NJ + e_jj) * BT + e_mm) * FF + e_ff];
      e0 = A_LD(psrc + 0); e1 = A_LD(psrc + 1);
    }

    if (run) {
      const bool enc = (g < 1024);
      // encoder inputs: raw bf16 hi/lo fragments (pre-split at setup)
      s16x8 xh0 = {}, xl0 = {}, xh1 = {}, xl1 = {};
      if (enc) {
        const size_t xo = ((size_t)(i * BT + ln15) * TT + g) * FF + lq * 8;
        xh0 = *(const s16x8*)&g_tsh[xo];
        xh1 = *(const s16x8*)&g_tsh[xo + 32];
        xl0 = *(const s16x8*)&g_tsl[xo];
        xl1 = *(const s16x8*)&g_tsl[xo + 32];
      }

      u64 q[16];
      const u64* ph = g_hpak
          + (size_t)((g & 3) * BB + i * BT + (wv << 2)) * (HH / 2) + lane;
      // issue ALL 16 loads (A first), then spin on HALF A only.
      LDA(0); LDA(1); LDA(2); LDA(3);
      LDB(0); LDB(1); LDB(2); LDB(3);
      bool a0 = BADA(0), a1 = BADA(1), a2 = BADA(2), a3 = BADA(3);
      bool b0 = BADB(0), b1 = BADB(1), b2 = BADB(2), b3 = BADB(3);
      while (a0 | a1 | a2 | a3) {
        __builtin_amdgcn_s_sleep(1);
        if (a0) LDA(0);
        if (a1) LDA(1);
        if (a2) LDA(2);
        if (a3) LDA(3);
        // opportunistic refresh of still-bad B rows (keeps B fresh for later)
        if (b0) LDB(0);
        if (b1) LDB(1);
        if (b2) LDB(2);
        if (b3) LDB(3);
        if (a0) a0 = BADA(0);
        if (a1) a1 = BADA(1);
        if (a2) a2 = BADA(2);
        if (a3) a3 = BADA(3);
        if (b0) b0 = BADB(0);
        if (b1) b1 = BADB(1);
        if (b2) b2 = BADB(2);
        if (b3) b3 = BADB(3);
      }
      // unpack HALF A (units 0-255) -> hi/lo LDS planes; lane-consecutive
      u16* sHw = &sHB[g & 1][0];
#pragma unroll
      for (int r = 0; r < 4; ++r) {
        const int row = (wv << 2) + r;
#pragma unroll
        for (int j2 = 0; j2 < 2; ++j2) {
          u64 v = q[4 * r + j2];
          u32 w0 = (u32)v, w1 = (u32)(v >> 32);
          u32 hi = __builtin_amdgcn_perm(w1, w0, 0x05040100u);
          u32 lo = __builtin_amdgcn_perm(w1, w0, 0x07060302u);
          const int u0 = 128 * j2 + 2 * lane;
          *(u32*)&sHw[row * LDK + u0] = hi;
          *(u32*)&sHw[(16 + row) * LDK + u0] = lo;
        }
      }
      BAR();   // half-A visible

      // 6 accumulator chains; MFMA over kt 0-7 (units 0-255) + encoder-x,
      // overlapping half-B's remaining arrival latency.
      f32x4 a0a = {bias, bias, bias, bias};
      f32x4 a0b = {0.f,0.f,0.f,0.f}, a1a = {0.f,0.f,0.f,0.f}, a1b = {0.f,0.f,0.f,0.f};
      f32x4 a2a = {0.f,0.f,0.f,0.f}, a2b = {0.f,0.f,0.f,0.f};
      const u16* sHb = &sHB[g & 1][0];
#pragma unroll
      for (int kt = 0; kt < 8; kt += 2) {
        {
          s16x8 ah = *(const s16x8*)&sHb[arow + kt * 32 + koff];
          s16x8 al = *(const s16x8*)&sHb[16 * LDK + arow + kt * 32 + koff];
          a0a = MFMA(ah, wh[kt], a0a, 0, 0, 0);
          a1a = MFMA(al, wh[kt], a1a, 0, 0, 0);
          a2a = MFMA(ah, wl[kt], a2a, 0, 0, 0);
        }
        {
          s16x8 ah = *(const s16x8*)&sHb[arow + (kt + 1) * 32 + koff];
          s16x8 al = *(const s16x8*)&sHb[16 * LDK + arow + (kt + 1) * 32 + koff];
          a0b = MFMA(ah, wh[kt + 1], a0b, 0, 0, 0);
          a1b = MFMA(al, wh[kt + 1], a1b, 0, 0, 0);
          a2b = MFMA(ah, wl[kt + 1], a2b, 0, 0, 0);
        }
      }
      if (enc) {
        a0a = MFMA(xh0, bxh0, a0a, 0, 0, 0);
        a0b = MFMA(xh1, bxh1, a0b, 0, 0, 0);
        a1a = MFMA(xl0, bxh0, a1a, 0, 0, 0);
        a1b = MFMA(xl1, bxh1, a1b, 0, 0, 0);
        a2a = MFMA(xh0, bxl0, a2a, 0, 0, 0);
        a2b = MFMA(xh1, bxl1, a2b, 0, 0, 0);
      }

      // ---- spin on HALF B (first check free: data already in registers) ----
      while (b0 | b1 | b2 | b3) {
        __builtin_amdgcn_s_sleep(1);
        if (b0) { LDB(0); b0 = BADB(0); }
        if (b1) { LDB(1); b1 = BADB(1); }
        if (b2) { LDB(2); b2 = BADB(2); }
        if (b3) { LDB(3); b3 = BADB(3); }
      }
      // unpack HALF B (units 256-511)
#pragma unroll
      for (int r = 0; r < 4; ++r) {
        const int row = (wv << 2) + r;
#pragma unroll
        for (int j2 = 2; j2 < 4; ++j2) {
          u64 v = q[4 * r + j2];
          u32 w0 = (u32)v, w1 = (u32)(v >> 32);
          u32 hi = __builtin_amdgcn_perm(w1, w0, 0x05040100u);
          u32 lo = __builtin_amdgcn_perm(w1, w0, 0x07060302u);
          const int u0 = 128 * j2 + 2 * lane;
          *(u32*)&sHw[row * LDK + u0] = hi;
          *(u32*)&sHw[(16 + row) * LDK + u0] = lo;
        }
      }
      BAR();   // half-B visible

#pragma unroll
      for (int kt = 8; kt < 16; kt += 2) {
        {
          s16x8 ah = *(const s16x8*)&sHb[arow + kt * 32 + koff];
          s16x8 al = *(const s16x8*)&sHb[16 * LDK + arow + kt * 32 + koff];
          a0a = MFMA(ah, wh[kt], a0a, 0, 0, 0);
          a1a = MFMA(al, wh[kt], a1a, 0, 0, 0);
          a2a = MFMA(ah, wl[kt], a2a, 0, 0, 0);
        }
        {
          s16x8 ah = *(const s16x8*)&sHb[arow + (kt + 1) * 32 + koff];
          s16x8 al = *(const s16x8*)&sHb[16 * LDK + arow + (kt + 1) * 32 + koff];
          a0b = MFMA(ah, wh[kt + 1], a0b, 0, 0, 0);
          a1b = MFMA(al, wh[kt + 1], a1b, 0, 0, 0);
          a2b = MFMA(ah, wl[kt + 1], a2b, 0, 0, 0);
        }
      }
      f32x4 vs = (a0a + a0b) + (a1a + a1b) + (a2a + a2b);

      // ---- in-register 4x4 gate transpose (butterfly over lane bits 2,3) ----
      float A0 = vs.x, A1 = vs.y, A2 = vs.z, A3 = vs.w;
      float t0 = __shfl_xor(A2, 8), t1 = __shfl_xor(A3, 8);
      float t2 = __shfl_xor(A0, 8), t3 = __shfl_xor(A1, 8);
      const bool hi2 = (tb & 2) != 0;
      float B0 = hi2 ? t0 : A0, B1 = hi2 ? t1 : A1;
      float B2 = hi2 ? A2 : t2, B3 = hi2 ? A3 : t3;
      float u0 = __shfl_xor(B1, 4), u1 = __shfl_xor(B0, 4);
      float u2 = __shfl_xor(B3, 4), u3 = __shfl_xor(B2, 4);
      const bool hi1 = (tb & 1) != 0;
      float gi = hi1 ? u0 : B0, gf = hi1 ? B1 : u1;
      float gg = hi1 ? u2 : B2, go = hi1 ? B3 : u3;

      float si = fsig(gi), sf = fsig(gf), tg = ftanh(gg), so_ = fsig(go);
      c_st = sf * c_st + si * tg;
      hn = so_ * ftanh(c_st);
      {
        u16 h0p = f2bf(hn), l0p = f2bf(hn - bf2f(h0p));
        u32 pak = (u32)h0p | ((u32)l0p << 16);
        u32 oth = __shfl_down(pak, 1);   // pair with unit u_own+1 (lane+1)
        // single per-step drain: partials(g-1)/outputs retired before h(g+1)
        // publishes. Outstanding stores here are ~1 step old -> near-free.
        asm volatile("s_waitcnt vmcnt(0)" ::: "memory");
        if ((ln15 & 1) == 0) {
          A_ST(&g_hpak[(size_t)(((g + 1) & 3)) * (BB * HH / 2) + colrow],
               (u64)pak | ((u64)oth << 32));
          // re-sentinel slot (g+3)&3: same thread+address as its future publish
          A_ST(&g_hpak[(size_t)(((g + 3) & 3)) * (BB * HH / 2) + colrow],
               0xFFFFFFFFFFFFFFFFull);
        }
      }
      // emit loads (issued post-publish; consumed after the partials block)
      if (demit) {
        const int slot = (g - 2) & 3;
        const u64* psrc = (const u64*)&g_part[
            (size_t)((((slot * NI) + i) * NJ + e_jj) * BT + e_mm) * FF + e_ff];
        e0 = A_LD(psrc + 0); e1 = A_LD(psrc + 1);
      }
    }

    // ---- off-critical-path: y-partials (2-step lag to emission) ----
    if (g >= 1023 && g < 2047) {   // partials of this step's h, slot g&3
      sHn[b_own][u_own] = hn;
      BAR();
      const int fg = tid & 15, mm = tid >> 4;
      float p0 = 0.f, p1 = 0.f, p2 = 0.f, p3 = 0.f;
#pragma unroll
      for (int n = 0; n < 16; ++n) {
        float hv = sHn[mm][n];
        const f32x4 w = *(const f32x4*)&sWoT[n][fg << 2];   // b128, conflict-free
        p0 += hv * w.x; p1 += hv * w.y; p2 += hv * w.z; p3 += hv * w.w;
      }
      union { float f[4]; u64 d[2]; } pu;
      pu.f[0] = p0; pu.f[1] = p1; pu.f[2] = p2; pu.f[3] = p3;
      u64* pp = (u64*)&g_part[(size_t)((((g & 3) * NI + i) * NJ + j) * BT + mm) * FF + (fg << 2)];
      A_ST(pp + 0, pu.d[0]); A_ST(pp + 1, pu.d[1]);
    }
    if (demit) {   // consume emit loads (latency hidden under partials block)
      const int k = g - 1025;
      union { u64 d[2]; float f[4]; } uu; uu.d[0] = e0; uu.d[1] = e1;
      float s0 = uu.f[0], s1 = uu.f[1], s2 = uu.f[2], s3 = uu.f[3];
#pragma unroll
      for (int m = 16; m >= 1; m >>= 1) {      // reduce over the 32 e_jj lanes
        s0 += __shfl_xor(s0, m); s1 += __shfl_xor(s1, m);
        s2 += __shfl_xor(s2, m); s3 += __shfl_xor(s3, m);
      }
      if (e_jj == 0) {
        float o0 = s0 + eb0, o1 = s1 + eb1, o2 = s2 + eb2, o3 = s3 + eb3;
        size_t oidx = ((size_t)(i * BT + e_mm) * TT + (1023 - k)) * FF + e_ff;
        if (isbf) {
          union { u16 h[4]; u64 d; } ov;
          ov.h[0] = f2bf(o0); ov.h[1] = f2bf(o1); ov.h[2] = f2bf(o2); ov.h[3] = f2bf(o3);
          *(u64*)((u16*)outv + oidx) = ov.d;
        } else {
          f32x4 ov = {o0, o1, o2, o3};
          *(f32x4*)((float*)outv + oidx) = ov;
        }
      }
    }

    // phase switch: reload registers with fused decoder weights
    if (g == 1023) {
#pragma unroll
      for (int kt = 0; kt < 16; ++kt) {
        const float* p = &g_weff[(size_t)gr0 * HH + kt * 32 + lq * 8];
#pragma unroll
        for (int q2 = 0; q2 < 8; ++q2) {
          float w = p[q2]; u16 hi = f2bf(w);
          wh[kt][q2] = (short)hi; wl[kt][q2] = (short)f2bf(w - bf2f(hi));
        }
      }
      bias = g_beff[gr0];
      c_st = 0.f;
    }
  }
}

extern "C" void kernel_launch(void* const* d_in, const int* in_sizes, int n_in,
                              void* d_out, int out_size, void* d_ws, size_t ws_size,
                              hipStream_t stream) {
  sniff_kernel<<<1, 64, 0, stream>>>(d_in[9]);  // w_out

  const int sizes[11] = { BB * TT * FF, G4 * FF, G4 * HH, G4, G4,
                          G4 * FF, G4 * HH, G4, G4, FF * HH, FF };
  for (int k = 0; k < 11; ++k)
    convert_kernel<<<(sizes[k] + 255) / 256, 256, 0, stream>>>(d_in[k], k, sizes[k]);

  prep_kernel<<<(G4 * HH) / 256, 256, 0, stream>>>();
  hinit_kernel<<<(2 * BB * HH) / 256, 256, 0, stream>>>();

  lstm_persist<<<NBLK, 256, 0, stream>>>(d_out);
}

// Round 11
// 6198.843 us; speedup vs baseline: 2.2934x; 1.0277x over previous
//
#include <hip/hip_runtime.h>
#include <math.h>

#define BB 128
#define TT 1024
#define FF 64
#define HH 512
#define G4 2048            // 4*HH gate rows
#define NI 8               // batch groups (independent)
#define NJ 32              // hidden slices per group (16 units each)
#define BT 16
#define NBLK 256
#define LDK 520            // padded LDS row (u16): 1040B stride
#define SENT 0xFFFFFFFFu   // impossible packed h (hi = bf16 NaN)

typedef float f32x4 __attribute__((ext_vector_type(4)));
typedef short s16x8 __attribute__((ext_vector_type(8)));
typedef unsigned short u16;
typedef unsigned int u32;
typedef unsigned long long u64;

// ---- canonical inputs (ts pre-split into bf16 hi/lo planes) ----
__device__ u16 g_tsh[BB * TT * FF];
__device__ u16 g_tsl[BB * TT * FF];
__device__ float g_wihe[G4 * FF];
__device__ float g_whhe[G4 * HH];
__device__ float g_bihe[G4], g_bhhe[G4], g_bihd[G4], g_bhhd[G4];
__device__ float g_wihd[G4 * FF];
__device__ float g_whhd[G4 * HH];
__device__ float g_wout[FF * HH];
__device__ float g_bout[FF];
// ---- precomputed fused decoder weights ----
__device__ float g_weff[G4 * HH];
__device__ float g_beff[G4];
// ---- inter-block state (agent-scope atomics only; h self-flags via SENT) ----
__device__ __align__(16) u64 g_hpak[2 * BB * HH];              // 4-slot ring (u64 units)
__device__ __align__(16) float g_part[4 * NI * NJ * BT * FF];  // depth-4 ring
__device__ int g_isbf16;

__device__ __forceinline__ float bf2f(u16 u) {
  union { unsigned u; float f; } x; x.u = ((unsigned)u) << 16; return x.f;
}
__device__ __forceinline__ u16 f2bf(float f) {
  union { float f; unsigned u; } x; x.f = f;
  unsigned r = x.u + 0x7fffu + ((x.u >> 16) & 1u);
  return (u16)(r >> 16);
}
// fast activations: 1-instr v_exp + v_rcp; saturate correctly at +/-inf
__device__ __forceinline__ float fsig(float x) {
  return __builtin_amdgcn_rcpf(1.f + __expf(-x));
}
__device__ __forceinline__ float ftanh(float x) {
  return 1.f - 2.f * __builtin_amdgcn_rcpf(__expf(2.f * x) + 1.f);
}

__global__ void sniff_kernel(const void* wout) {
  __shared__ int cnt[64];
  int t = threadIdx.x;
  const unsigned* d = (const unsigned*)wout;
  int c = 0;
  for (int k = t; k < 1024; k += 64) {
    unsigned b = (d[k] >> 8) & 0x7fu;
    c += (b >= 0x30u && b <= 0x3eu) ? 1 : 0;
  }
  cnt[t] = c;
  __syncthreads();
  if (t == 0) {
    int s = 0;
    for (int k = 0; k < 64; ++k) s += cnt[k];
    g_isbf16 = (s > 512) ? 1 : 0;
  }
}

__global__ void convert_kernel(const void* __restrict__ src, int which, int n) {
  int idx = blockIdx.x * 256 + threadIdx.x;
  if (idx >= n) return;
  float v;
  if (g_isbf16) v = bf2f(((const u16*)src)[idx]);
  else          v = ((const float*)src)[idx];
  if (which == 0) {               // ts -> bf16 hi/lo planes (encoder loads raw fragments)
    u16 hi = f2bf(v);
    g_tsh[idx] = hi;
    g_tsl[idx] = f2bf(v - bf2f(hi));
    return;
  }
  float* dst;
  switch (which) {
    case 1: dst = g_wihe; break;
    case 2: dst = g_whhe; break;
    case 3: dst = g_bihe; break;
    case 4: dst = g_bhhe; break;
    case 5: dst = g_wihd; break;
    case 6: dst = g_whhd; break;
    case 7: dst = g_bihd; break;
    case 8: dst = g_bhhd; break;
    case 9: dst = g_wout; break;
    default: dst = g_bout; break;
  }
  dst[idx] = v;
}

__global__ void prep_kernel() {
  int idx = blockIdx.x * 256 + threadIdx.x;
  int r = idx >> 9, c = idx & 511;
  float acc = g_whhd[idx];
  const float* wr = &g_wihd[r * FF];
  for (int f = 0; f < FF; ++f) acc += wr[f] * g_wout[f * HH + c];
  g_weff[idx] = acc;
  if (idx < G4) {
    float b = g_bihd[idx] + g_bhhd[idx];
    for (int f = 0; f < FF; ++f) b += g_wihd[idx * FF + f] * g_bout[f];
    g_beff[idx] = b;
  }
}

// per-launch ring init (u64 units): slot 0 = h(0)=0, slots 1-3 = sentinel.
__global__ void hinit_kernel() {
  int idx = blockIdx.x * 256 + threadIdx.x;   // 0 .. 2*BB*HH-1
  g_hpak[idx] = (idx < (BB * HH / 2)) ? 0ull : 0xFFFFFFFFFFFFFFFFull;
}

#define MFMA __builtin_amdgcn_mfma_f32_16x16x32_bf16
#define A_LD(p)  __hip_atomic_load((p), __ATOMIC_RELAXED, __HIP_MEMORY_SCOPE_AGENT)
#define A_ST(p, v) __hip_atomic_store((p), (v), __ATOMIC_RELAXED, __HIP_MEMORY_SCOPE_AGENT)

// Raw barrier: LDS ordering only. __syncthreads() would drain vmcnt(0) every
// time (store-acks ~1-2k cy) — keep vmem drains off the critical path.
#define BAR() do { asm volatile("s_waitcnt lgkmcnt(0)" ::: "memory"); \
                   __builtin_amdgcn_s_barrier(); } while (0)

// WAVE-COALESCED poll: load #(4R+j2) across 64 lanes covers 512B CONTIGUOUS
// (lane l at +l). Old layout was 128B-strided per instruction -> 64 line
// touches x 8B used = ~8x fabric inflation on uncacheable (agent) loads.
#define LDR(R) do { \
    q[4*(R)+0] = A_LD(ph + (R)*256 +   0); \
    q[4*(R)+1] = A_LD(ph + (R)*256 +  64); \
    q[4*(R)+2] = A_LD(ph + (R)*256 + 128); \
    q[4*(R)+3] = A_LD(ph + (R)*256 + 192); } while (0)
#define BADR(R) ( ((u32)q[4*(R)+0]==SENT) | ((u32)(q[4*(R)+0]>>32)==SENT) | \
                  ((u32)q[4*(R)+1]==SENT) | ((u32)(q[4*(R)+1]>>32)==SENT) | \
                  ((u32)q[4*(R)+2]==SENT) | ((u32)(q[4*(R)+2]>>32)==SENT) | \
                  ((u32)q[4*(R)+3]==SENT) | ((u32)(q[4*(R)+3]>>32)==SENT) )

__global__ __launch_bounds__(256, 1) void lstm_persist(void* __restrict__ outv) {
  // double-buffered h staging: one stage barrier per step; dbuf prevents
  // unpack(g+1) racing MFMA-reads(g).
  __shared__ u16 sHB[2][32 * LDK];  // rows 0-15: h_hi, 16-31: h_lo (linear layout)
  __shared__ float sHn[16][17];     // h_new f32 for y-partials
  __shared__ float sWoT[16][64];    // TRANSPOSED w_out slice: sWoT[n][f]

  const int tid = threadIdx.x, bid = blockIdx.x;
  const int i = bid & 7, j = bid >> 3;      // group i ~ XCD-affine, j 0..31
  const int wv = tid >> 6, lane = tid & 63;
  const int ln15 = lane & 15, lq = lane >> 4;
  // gaterow assignment: wave wv owns units {4wv..4wv+3}; lane col c=ln15
  // encodes (gate gc = c>>2, unit uc = c&3). All 4 gates of a unit live in the
  // SAME wave -> gate exchange is a 2-stage shfl_xor butterfly, no LDS/barrier.
  const int gc = ln15 >> 2, uc = ln15 & 3;
  const int gr0 = gc * 512 + (j << 4) + (wv << 2) + uc;
  const int tb = gc;                            // transpose row-block index
  const int b_own = 4 * lq + tb;                // this lane's batch row (post-butterfly)
  const int u_own = (wv << 2) + uc;             // this lane's unit within block
  const size_t colrow = (size_t)(i * BT + b_own) * (HH / 2) + (j << 3) + (u_own >> 1);
  const bool isbf = (g_isbf16 != 0);

  // ---- hidden weights -> registers (hi/lo bf16), encoder phase ----
  s16x8 wh[16], wl[16];
#pragma unroll
  for (int kt = 0; kt < 16; ++kt) {
    const float* p = &g_whhe[(size_t)gr0 * HH + kt * 32 + lq * 8];
#pragma unroll
    for (int q2 = 0; q2 < 8; ++q2) {
      float w = p[q2]; u16 hi = f2bf(w);
      wh[kt][q2] = (short)hi; wl[kt][q2] = (short)f2bf(w - bf2f(hi));
    }
  }
  s16x8 bxh0, bxh1, bxl0, bxl1;   // encoder x-weight fragments
  {
    const float* p0 = &g_wihe[(size_t)gr0 * FF + lq * 8];
#pragma unroll
    for (int q2 = 0; q2 < 8; ++q2) {
      float w0 = p0[q2], w1 = p0[32 + q2];
      u16 h0 = f2bf(w0), h1 = f2bf(w1);
      bxh0[q2] = (short)h0; bxl0[q2] = (short)f2bf(w0 - bf2f(h0));
      bxh1[q2] = (short)h1; bxl1[q2] = (short)f2bf(w1 - bf2f(h1));
    }
  }
  for (int idx = tid; idx < 16 * 64; idx += 256) {
    int n = idx >> 6, f = idx & 63;
    sWoT[n][f] = g_wout[f * HH + (j << 4) + n];
  }
  float bias = g_bihe[gr0] + g_bhhe[gr0];

  // ---- emission geometry (balanced across ALL 32 j-blocks, 256 threads) ----
  const int e_jj = tid & 31;                 // partial-slice index
  const int e_cell = (j << 3) + (tid >> 5);  // 0..255 output cell (mm, ffq)
  const int e_mm = e_cell >> 4, e_ff = (e_cell & 15) << 2;
  const float eb0 = g_bout[e_ff + 0], eb1 = g_bout[e_ff + 1];
  const float eb2 = g_bout[e_ff + 2], eb3 = g_bout[e_ff + 3];

  float c_st = 0.f;
  const int arow = ln15 * LDK;
  const int koff = lq * 8;

  for (int g = 0; g <= 2048; ++g) {
    const bool run = (g < 2048);
    float hn = 0.f;
    u64 e0 = 0, e1 = 0;
    const bool demit = (g >= 1025);

    if (!run && demit) {   // final drain iteration: issue emit loads up front
      const int slot = (g - 2) & 3;
      const u64* psrc = (const u64*)&g_part[
          (size_t)((((slot * NI) + i) * NJ + e_jj) * BT + e_mm) * FF + e_ff];
      e0 = A_LD(psrc + 0); e1 = A_LD(psrc + 1);
    }

    if (run) {
      const bool enc = (g < 1024);
      // encoder inputs: raw bf16 hi/lo fragments (pre-split at setup)
      s16x8 xh0 = {}, xl0 = {}, xh1 = {}, xl1 = {};
      if (enc) {
        const size_t xo = ((size_t)(i * BT + ln15) * TT + g) * FF + lq * 8;
        xh0 = *(const s16x8*)&g_tsh[xo];
        xh1 = *(const s16x8*)&g_tsh[xo + 32];
        xl0 = *(const s16x8*)&g_tsl[xo];
        xl1 = *(const s16x8*)&g_tsl[xo + 32];
      }

      // ---- POLL-STAGE h(g) from ring slot g&3 (data self-flags).
      // Wave wv covers its 4 rows (4wv..4wv+3) as 16 coalesced 512B rounds:
      // q[4r+j2] = units {128*j2+2*lane, +1} of row 4wv+r.
      u64 q[16];
      {
        const u64* ph = g_hpak
            + (size_t)((g & 3) * BB + i * BT + (wv << 2)) * (HH / 2) + lane;
        LDR(0); LDR(1); LDR(2); LDR(3);
        bool b0 = BADR(0), b1 = BADR(1), b2 = BADR(2), b3 = BADR(3);
        while (b0 | b1 | b2 | b3) {
          __builtin_amdgcn_s_sleep(1);
          if (b0) { LDR(0); b0 = BADR(0); }
          if (b1) { LDR(1); b1 = BADR(1); }
          if (b2) { LDR(2); b2 = BADR(2); }
          if (b3) { LDR(3); b3 = BADR(3); }
        }
      }
      // unpack packed u32 -> hi/lo LDS planes (v_perm); linear scatter,
      // lane-consecutive ds_write_b32 (conflict-free, no swizzle needed)
      {
        u16* sHw = &sHB[g & 1][0];
#pragma unroll
        for (int r = 0; r < 4; ++r) {
          const int row = (wv << 2) + r;
#pragma unroll
          for (int j2 = 0; j2 < 4; ++j2) {
            u64 v = q[4 * r + j2];
            u32 w0 = (u32)v, w1 = (u32)(v >> 32);
            u32 hi = __builtin_amdgcn_perm(w1, w0, 0x05040100u);
            u32 lo = __builtin_amdgcn_perm(w1, w0, 0x07060302u);
            const int u0 = 128 * j2 + 2 * lane;
            *(u32*)&sHw[row * LDK + u0] = hi;
            *(u32*)&sHw[(16 + row) * LDK + u0] = lo;
          }
        }
      }
      BAR();   // lgkmcnt-only barrier: NO vmem drain on the critical path

      // 6 accumulator chains: MFMA dep latency fully hidden
      f32x4 a0a = {bias, bias, bias, bias};
      f32x4 a0b = {0.f,0.f,0.f,0.f}, a1a = {0.f,0.f,0.f,0.f}, a1b = {0.f,0.f,0.f,0.f};
      f32x4 a2a = {0.f,0.f,0.f,0.f}, a2b = {0.f,0.f,0.f,0.f};
      const u16* sHb = &sHB[g & 1][0];
#pragma unroll
      for (int kt = 0; kt < 16; kt += 2) {
        {
          s16x8 ah = *(const s16x8*)&sHb[arow + kt * 32 + koff];
          s16x8 al = *(const s16x8*)&sHb[16 * LDK + arow + kt * 32 + koff];
          a0a = MFMA(ah, wh[kt], a0a, 0, 0, 0);
          a1a = MFMA(al, wh[kt], a1a, 0, 0, 0);
          a2a = MFMA(ah, wl[kt], a2a, 0, 0, 0);
        }
        {
          s16x8 ah = *(const s16x8*)&sHb[arow + (kt + 1) * 32 + koff];
          s16x8 al = *(const s16x8*)&sHb[16 * LDK + arow + (kt + 1) * 32 + koff];
          a0b = MFMA(ah, wh[kt + 1], a0b, 0, 0, 0);
          a1b = MFMA(al, wh[kt + 1], a1b, 0, 0, 0);
          a2b = MFMA(ah, wl[kt + 1], a2b, 0, 0, 0);
        }
      }
      if (enc) {
        a0a = MFMA(xh0, bxh0, a0a, 0, 0, 0);
        a0b = MFMA(xh1, bxh1, a0b, 0, 0, 0);
        a1a = MFMA(xl0, bxh0, a1a, 0, 0, 0);
        a1b = MFMA(xl1, bxh1, a1b, 0, 0, 0);
        a2a = MFMA(xh0, bxl0, a2a, 0, 0, 0);
        a2b = MFMA(xh1, bxl1, a2b, 0, 0, 0);
      }
      f32x4 vs = (a0a + a0b) + (a1a + a1b) + (a2a + a2b);

      // ---- in-register 4x4 gate transpose (butterfly over lane bits 2,3) ----
      float A0 = vs.x, A1 = vs.y, A2 = vs.z, A3 = vs.w;
      float t0 = __shfl_xor(A2, 8), t1 = __shfl_xor(A3, 8);
      float t2 = __shfl_xor(A0, 8), t3 = __shfl_xor(A1, 8);
      const bool hi2 = (tb & 2) != 0;
      float B0 = hi2 ? t0 : A0, B1 = hi2 ? t1 : A1;
      float B2 = hi2 ? A2 : t2, B3 = hi2 ? A3 : t3;
      float u0 = __shfl_xor(B1, 4), u1 = __shfl_xor(B0, 4);
      float u2 = __shfl_xor(B3, 4), u3 = __shfl_xor(B2, 4);
      const bool hi1 = (tb & 1) != 0;
      float gi = hi1 ? u0 : B0, gf = hi1 ? B1 : u1;
      float gg = hi1 ? u2 : B2, go = hi1 ? B3 : u3;

      float si = fsig(gi), sf = fsig(gf), tg = ftanh(gg), so_ = fsig(go);
      c_st = sf * c_st + si * tg;
      hn = so_ * ftanh(c_st);
      {
        u16 h0p = f2bf(hn), l0p = f2bf(hn - bf2f(h0p));
        u32 pak = (u32)h0p | ((u32)l0p << 16);
        u32 oth = __shfl_down(pak, 1);   // pair with unit u_own+1 (lane+1)
        // single per-step drain: partials(g-1)/outputs retired before h(g+1)
        // publishes. Outstanding stores here are ~1 step old -> near-free.
        asm volatile("s_waitcnt vmcnt(0)" ::: "memory");
        if ((ln15 & 1) == 0) {
          A_ST(&g_hpak[(size_t)(((g + 1) & 3)) * (BB * HH / 2) + colrow],
               (u64)pak | ((u64)oth << 32));
          // re-sentinel slot (g+3)&3: same thread+address as its future publish
          A_ST(&g_hpak[(size_t)(((g + 3) & 3)) * (BB * HH / 2) + colrow],
               0xFFFFFFFFFFFFFFFFull);
        }
      }
      // emit loads (issued post-publish; consumed after the partials block)
      if (demit) {
        const int slot = (g - 2) & 3;
        const u64* psrc = (const u64*)&g_part[
            (size_t)((((slot * NI) + i) * NJ + e_jj) * BT + e_mm) * FF + e_ff];
        e0 = A_LD(psrc + 0); e1 = A_LD(psrc + 1);
      }
    }

    // ---- off-critical-path: y-partials (2-step lag to emission) ----
    if (g >= 1023 && g < 2047) {   // partials of this step's h, slot g&3
      sHn[b_own][u_own] = hn;
      BAR();
      const int fg = tid & 15, mm = tid >> 4;
      float p0 = 0.f, p1 = 0.f, p2 = 0.f, p3 = 0.f;
#pragma unroll
      for (int n = 0; n < 16; ++n) {
        float hv = sHn[mm][n];
        const f32x4 w = *(const f32x4*)&sWoT[n][fg << 2];   // b128, conflict-free
        p0 += hv * w.x; p1 += hv * w.y; p2 += hv * w.z; p3 += hv * w.w;
      }
      union { float f[4]; u64 d[2]; } pu;
      pu.f[0] = p0; pu.f[1] = p1; pu.f[2] = p2; pu.f[3] = p3;
      u64* pp = (u64*)&g_part[(size_t)((((g & 3) * NI + i) * NJ + j) * BT + mm) * FF + (fg << 2)];
      A_ST(pp + 0, pu.d[0]); A_ST(pp + 1, pu.d[1]);
    }
    if (demit) {   // consume emit loads (latency hidden under partials block)
      const int k = g - 1025;
      union { u64 d[2]; float f[4]; } uu; uu.d[0] = e0; uu.d[1] = e1;
      float s0 = uu.f[0], s1 = uu.f[1], s2 = uu.f[2], s3 = uu.f[3];
#pragma unroll
      for (int m = 16; m >= 1; m >>= 1) {      // reduce over the 32 e_jj lanes
        s0 += __shfl_xor(s0, m); s1 += __shfl_xor(s1, m);
        s2 += __shfl_xor(s2, m); s3 += __shfl_xor(s3, m);
      }
      if (e_jj == 0) {
        float o0 = s0 + eb0, o1 = s1 + eb1, o2 = s2 + eb2, o3 = s3 + eb3;
        size_t oidx = ((size_t)(i * BT + e_mm) * TT + (1023 - k)) * FF + e_ff;
        if (isbf) {
          union { u16 h[4]; u64 d; } ov;
          ov.h[0] = f2bf(o0); ov.h[1] = f2bf(o1); ov.h[2] = f2bf(o2); ov.h[3] = f2bf(o3);
          *(u64*)((u16*)outv + oidx) = ov.d;
        } else {
          f32x4 ov = {o0, o1, o2, o3};
          *(f32x4*)((float*)outv + oidx) = ov;
        }
      }
    }

    // phase switch: reload registers with fused decoder weights
    if (g == 1023) {
#pragma unroll
      for (int kt = 0; kt < 16; ++kt) {
        const float* p = &g_weff[(size_t)gr0 * HH + kt * 32 + lq * 8];
#pragma unroll
        for (int q2 = 0; q2 < 8; ++q2) {
          float w = p[q2]; u16 hi = f2bf(w);
          wh[kt][q2] = (short)hi; wl[kt][q2] = (short)f2bf(w - bf2f(hi));
        }
      }
      bias = g_beff[gr0];
      c_st = 0.f;
    }
  }
}

extern "C" void kernel_launch(void* const* d_in, const int* in_sizes, int n_in,
                              void* d_out, int out_size, void* d_ws, size_t ws_size,
                              hipStream_t stream) {
  sniff_kernel<<<1, 64, 0, stream>>>(d_in[9]);  // w_out

  const int sizes[11] = { BB * TT * FF, G4 * FF, G4 * HH, G4, G4,
                          G4 * FF, G4 * HH, G4, G4, FF * HH, FF };
  for (int k = 0; k < 11; ++k)
    convert_kernel<<<(sizes[k] + 255) / 256, 256, 0, stream>>>(d_in[k], k, sizes[k]);

  prep_kernel<<<(G4 * HH) / 256, 256, 0, stream>>>();
  hinit_kernel<<<(2 * BB * HH) / 256, 256, 0, stream>>>();

  lstm_persist<<<NBLK, 256, 0, stream>>>(d_out);
}